// Round 26
// baseline (451.931 us; speedup 1.0000x reference)
//
#include <hip/hip_runtime.h>
#include <float.h>

#define KC 4096
#define DIM 256
#define MB 16384            // m per batch element (16*32*32)
#define NTOT 65536          // rows
#define ZELEMS 16777216
#define LOSS_OFF 16777216
#define IDX_OFF  16777217
// TAU: 2*(grid ULP(256)=3.05e-5) + 2*fp16-chain score err (<=4.7e-5 worst) + slack.
// Validated empirically at 1.5e-4 in R11-R25 (0 misses across 65536 rows).
#define TAU 1.5e-4f

// scratch inside z_q output region (fully overwritten by vq_apply at the end):
// [0, 524288)       fp16 e' A-fragment table (2MB)
#define BT_OFF   524288     // f32 |e_k|^2 table, 4096 floats
#define CNT_OFF  528400     // 2 uints (cand count, full count)
#define CAND_OFF 532480     // uint4 entries (16B each), cap 65536
#define FULL_OFF 800000     // uint entries, cap 65536
#define PART_OFF 900000     // per-(split,row,khi) 4xu64 sub-records, 16MB

typedef _Float16 h8 __attribute__((ext_vector_type(8)));
typedef float f4v __attribute__((ext_vector_type(4)));

__device__ __forceinline__ bool lexlt(float av, int ai, float bv, int bi) {
    return (av < bv) || (av == bv && ai < bi);
}

// ---- P: fused prep. Blocks 0-511: fp16 e'=e*4096 A-frag table (R10-R25
// verified geometry). Blocks 512-1535: |e|^2 (fp64->f32), one wave per code. ----
__global__ __launch_bounds__(256) void vq_prep(const float* __restrict__ e,
                                               float* __restrict__ out) {
    if (blockIdx.x < 512) {
        int t = blockIdx.x * 256 + threadIdx.x;        // 0..131071
        int code = t >> 5, s8 = t & 31;
        const float4* src = reinterpret_cast<const float4*>(e + (size_t)code * DIM + s8 * 8);
        float4 v0 = src[0], v1 = src[1];
        float f[8] = {v0.x, v0.y, v0.z, v0.w, v1.x, v1.y, v1.z, v1.w};
        union { uint4 q; _Float16 h[8]; } P;
        #pragma unroll
        for (int p = 0; p < 8; ++p) P.h[p] = (_Float16)(f[p] * 4096.0f);
        int kc = s8 >> 2, khi = s8 & 3;
        int lane = khi * 16 + (code & 15);
        int slot = ((code >> 4) * 8 + kc) * 64 + lane;
        reinterpret_cast<uint4*>(out)[slot] = P.q;
    } else {
        int k = (blockIdx.x - 512) * 4 + (threadIdx.x >> 6);   // 0..4095
        int lane = threadIdx.x & 63;
        float4 v = reinterpret_cast<const float4*>(e + (size_t)k * DIM)[lane];
        double s = (double)v.x * v.x + (double)v.y * v.y + (double)v.z * v.z + (double)v.w * v.w;
        #pragma unroll
        for (int off = 32; off > 0; off >>= 1) s += __shfl_down(s, off);
        if (lane == 0) out[BT_OFF + k] = (float)s;
    }
}

// sorted insert keeping the 4 SMALLEST pushed (v0<=v1<=v2<=v3); exact-loss
// guarantee (R18-validated): any evicted value >= v3, so a lost window member
// forces count>=5 -> full. ----
#define INS4(V0, V1, V2, V3, L0, L1, L2, L3, v, k)                              \
    if (v < V3) {                                                               \
        if (v < V2) {                                                           \
            V3 = V2; L3 = L2;                                                   \
            if (v < V1) {                                                       \
                V2 = V1; L2 = L1;                                               \
                if (v < V0) { V1 = V0; L1 = L0; V0 = v; L0 = k; }               \
                else        { V1 = v; L1 = k; }                                 \
            } else { V2 = v; L2 = k; }                                          \
        } else { V3 = v; L3 = k; }                                              \
    }

// ---- K1: fp16 MFMA, single-pass exact-window, K-SPLIT 2.
// Block = 64 rows x 2048 codes (split = bid&1). 2048 blocks = 8 blocks/CU
// (16KB LDS, 48 VGPR) -> 2x the R21-R25 wave pool. Per-lane local-window
// member lists written directly to scratch; vq_merge classifies. ----
__global__ __launch_bounds__(256) void vq_fast(const float* __restrict__ z,
                                               float* __restrict__ out) {
    __shared__ uint4 etile[2][512];                // 16KB double-buffered tile
    const int tid = threadIdx.x;
    const int wave = tid >> 6, lane = tid & 63;
    const int khi = lane >> 4, l16 = lane & 15;
    const int split = blockIdx.x & 1;
    const int rb = blockIdx.x >> 1;
    const int nbase = rb * 64;
    const int b = nbase / MB;
    const int mbase = nbase % MB;
    const float* zb = z + (size_t)b * DIM * MB + mbase + wave * 16 + l16;

    // z B-fragments (fp16), 1 row-set x 8 kc
    h8 zf[8];
    #pragma unroll
    for (int kc = 0; kc < 8; ++kc) {
        h8 va;
        #pragma unroll
        for (int j = 0; j < 8; ++j)
            va[j] = (_Float16)zb[(size_t)(kc * 32 + khi * 8 + j) * MB];
        zf[kc] = va;
    }

    const uint4* ET = reinterpret_cast<const uint4*>(out);
    const float* Btab = out + BT_OFF;

    float b1 = FLT_MAX;
    int bk = 0;
    float v0 = FLT_MAX, v1 = FLT_MAX, v2 = FLT_MAX, v3 = FLT_MAX;
    int l0 = 0, l1 = 0, l2 = 0, l3 = 0;

    const int t0 = split * (KC / 32);              // 128 tiles per split
    uint4 r0 = ET[(size_t)t0 * 512 + tid], r1 = ET[(size_t)t0 * 512 + tid + 256];
    for (int tile = t0; tile < t0 + KC / 32; ++tile) {
        const int cur = tile & 1;
        etile[cur][tid] = r0; etile[cur][tid + 256] = r1;
        __syncthreads();                           // only barrier per tile
        if (tile < t0 + KC / 32 - 1) {
            r0 = ET[(size_t)(tile + 1) * 512 + tid];
            r1 = ET[(size_t)(tile + 1) * 512 + tid + 256];
        }

        // 2 independent MFMA chains (kc even/odd)
        f4v ae = {0.f, 0.f, 0.f, 0.f}, ao = ae;
        #pragma unroll
        for (int kc = 0; kc < 8; kc += 2) {
            union { uint4 q; h8 v; } afe, afo;
            afe.q = etile[cur][kc * 64 + lane];
            afo.q = etile[cur][(kc + 1) * 64 + lane];
            ae = __builtin_amdgcn_mfma_f32_16x16x32_f16(afe.v, zf[kc], ae, 0, 0, 0);
            ao = __builtin_amdgcn_mfma_f32_16x16x32_f16(afo.v, zf[kc + 1], ao, 0, 0, 0);
        }

        const f4v Bv = *reinterpret_cast<const f4v*>(Btab + tile * 16 + khi * 4);
        const int kb = tile * 16 + khi * 4;
        float sc[4];
        #pragma unroll
        for (int i = 0; i < 4; ++i)
            sc[i] = fmaf(-4.8828125e-4f, ae[i] + ao[i], Bv[i]);    // -1/2048 exact
        float m = fminf(fminf(sc[0], sc[1]), fminf(sc[2], sc[3]));
        if (m <= b1 + TAU) {                       // rare: detail insert
            #pragma unroll
            for (int i = 0; i < 4; ++i) {
                float s = sc[i]; int k = kb + i;   // ascending k per lane
                if (s < b1) {
                    if (b1 <= s + TAU) INS4(v0, v1, v2, v3, l0, l1, l2, l3, b1, bk)
                    b1 = s; bk = k;
                } else if (s <= b1 + TAU) {
                    INS4(v0, v1, v2, v3, l0, l1, l2, l3, s, k)
                }
            }
        }
    }

    // merge top-1 across the 4 khi groups (lex) -> split-local best
    float gb = b1;
    int gk = bk;
    #pragma unroll
    for (int off = 16; off < 64; off <<= 1) {
        float ov = __shfl_xor(gb, off); int ok = __shfl_xor(gk, off);
        if (lexlt(ov, ok, gb, gk)) { gb = ov; gk = ok; }
    }
    const float thr = gb + TAU;                    // LOCAL threshold

    // pack own-lane local-window members (value,k) as u64s; count<=5, n in
    // bits 12..14 of entry 0 (k occupies bits 0..11)
    int n = 0;
    unsigned long long e0 = 0, e1 = 0, e2 = 0, e3 = 0;
    #define PUTP(vv, kk) { unsigned long long pk =                               \
            ((unsigned long long)__float_as_uint(vv) << 32) | (unsigned)(kk);    \
        if (n == 0) e0 = pk; else if (n == 1) e1 = pk;                           \
        else if (n == 2) e2 = pk; else if (n == 3) e3 = pk; n++; }
    if (b1 <= thr) PUTP(b1, bk)
    if (v0 <= thr) PUTP(v0, l0)
    if (v1 <= thr) PUTP(v1, l1)
    if (v2 <= thr) PUTP(v2, l2)
    if (v3 <= thr) PUTP(v3, l3)
    e0 |= (unsigned long long)n << 12;

    const int gidx = nbase + wave * 16 + l16;
    unsigned long long* P = reinterpret_cast<unsigned long long*>(out + PART_OFF) +
                            ((size_t)(split * NTOT + gidx) * 4 + khi) * 4;
    P[0] = e0; P[1] = e1; P[2] = e2; P[3] = e3;
}

// ---- K1b: merge the 2 splits' member lists per row, classify, emit ----
__global__ __launch_bounds__(256) void vq_merge(float* __restrict__ out) {
    const int r = blockIdx.x * 256 + threadIdx.x;
    const int lane = threadIdx.x & 63;
    const unsigned long long* P = reinterpret_cast<const unsigned long long*>(out + PART_OFF);

    unsigned long long ent[32];
    int num[8];
    #pragma unroll
    for (int sq = 0; sq < 8; ++sq) {
        int s = sq >> 2, q = sq & 3;
        const unsigned long long* sub = P + ((size_t)(s * NTOT + r) * 4 + q) * 4;
        ent[sq * 4 + 0] = sub[0]; ent[sq * 4 + 1] = sub[1];
        ent[sq * 4 + 2] = sub[2]; ent[sq * 4 + 3] = sub[3];
        num[sq] = (int)((ent[sq * 4] >> 12) & 7ull);
    }

    // global best (lex over all valid pairs; split0 ks < split1 ks)
    float gbv = FLT_MAX; int gbk = 0;
    #pragma unroll
    for (int sq = 0; sq < 8; ++sq) {
        #pragma unroll
        for (int j = 0; j < 4; ++j) {
            if (j < num[sq]) {
                unsigned long long pk = ent[sq * 4 + j];
                float v = __uint_as_float((unsigned)(pk >> 32));
                int k = (int)(pk & 0xFFFull);
                if (lexlt(v, k, gbv, gbk)) { gbv = v; gbk = k; }
            }
        }
    }
    const float thr = gbv + TAU;
    const int nt0 = num[0] + num[1] + num[2] + num[3];
    const int nt1 = num[4] + num[5] + num[6] + num[7];
    const bool ovf = (nt0 >= 5) || (nt1 >= 5);     // lost entries possible -> full

    // count + collect global members (pairs <= thr)
    int m = 0, c0 = gbk, c1 = gbk, c2 = gbk, c3 = gbk;
    #pragma unroll
    for (int sq = 0; sq < 8; ++sq) {
        #pragma unroll
        for (int j = 0; j < 4; ++j) {
            if (j < num[sq]) {
                unsigned long long pk = ent[sq * 4 + j];
                float v = __uint_as_float((unsigned)(pk >> 32));
                int k = (int)(pk & 0xFFFull);
                if (v <= thr) {
                    if (m == 0) c0 = k; else if (m == 1) c1 = k;
                    else if (m == 2) c2 = k; else if (m == 3) c3 = k;
                    m++;
                }
            }
        }
    }

    out[IDX_OFF + r] = (float)gbk;                 // final for clean; placeholder else
    bool full = ovf || (m > 4);
    bool cand = !full && (m >= 2);
    unsigned* cntg = (unsigned*)(out + CNT_OFF);
    unsigned long long mc = __ballot(cand);
    if (mc) {
        int leader = __ffsll((long long)mc) - 1;
        unsigned base = 0;
        if (lane == leader) base = atomicAdd(cntg, (unsigned)__popcll(mc));
        base = __shfl(base, leader);
        if (cand) {
            unsigned pos = base + (unsigned)__popcll(mc & ((1ull << lane) - 1ull));
            reinterpret_cast<uint4*>(out + CAND_OFF)[pos] =
                make_uint4((unsigned)r,
                           (unsigned)c0 | ((unsigned)c1 << 16),
                           (unsigned)c2 | ((unsigned)c3 << 16), 0u);
        }
    }
    unsigned long long mf = __ballot(full);
    if (mf) {
        int leader = __ffsll((long long)mf) - 1;
        unsigned base = 0;
        if (lane == leader) base = atomicAdd(cntg + 1, (unsigned)__popcll(mf));
        base = __shfl(base, leader);
        if (full) {
            unsigned pos = base + (unsigned)__popcll(mf & ((1ull << lane) - 1ull));
            reinterpret_cast<unsigned*>(out + FULL_OFF)[pos] = (unsigned)r;
        }
    }
}

// ---- K2: fused resolver. All blocks: full entries (block-strided), then
// cand entries (wave-strided). Both use the R5-exact formula, B from Btab. ----
__global__ __launch_bounds__(256) void vq_resolve(const float* __restrict__ z,
                                                  const float* __restrict__ e,
                                                  float* __restrict__ out) {
    __shared__ float zs[DIM];
    __shared__ float rv[4];
    __shared__ int ri[4];
    const int tid = threadIdx.x;
    const int wave = tid >> 6, lane = tid & 63;
    const float* Btab = out + BT_OFF;

    // ---- phase 1: full rescans (block per entry, grid-strided) ----
    const unsigned nf = reinterpret_cast<const unsigned*>(out + CNT_OFF)[1];
    const unsigned* flist = reinterpret_cast<const unsigned*>(out + FULL_OFF);
    for (unsigned ei = blockIdx.x; ei < nf; ei += gridDim.x) {
        const int gidx = (int)flist[ei];
        const int b = gidx >> 14, m = gidx & (MB - 1);
        const float* zr = z + (size_t)b * DIM * MB + m;
        if (tid < DIM) zs[tid] = zr[(size_t)tid * MB];
        __syncthreads();
        double av = 0.0;
        #pragma unroll
        for (int t2 = 0; t2 < 4; ++t2) {
            double zv = (double)zs[lane * 4 + t2];
            av = fma(zv, zv, av);
        }
        #pragma unroll
        for (int mm = 1; mm < 64; mm <<= 1) av += __shfl_xor(av, mm);
        const float Af = (float)av;

        float bsv = FLT_MAX; int bsk = 0;
        for (int kk = 0; kk < 16; ++kk) {
            const int k = kk * 256 + tid;          // ascending per thread
            const float4* er4 = reinterpret_cast<const float4*>(e + (size_t)k * DIM);
            const float4* zs4 = reinterpret_cast<const float4*>(zs);
            double dot0 = 0.0, dot1 = 0.0;
            #pragma unroll 8
            for (int d4 = 0; d4 < 64; ++d4) {
                float4 ev = er4[d4];
                float4 zv = zs4[d4];
                dot0 = fma((double)zv.x, (double)ev.x, dot0);
                dot1 = fma((double)zv.y, (double)ev.y, dot1);
                dot0 = fma((double)zv.z, (double)ev.z, dot0);
                dot1 = fma((double)zv.w, (double)ev.w, dot1);
            }
            float s = (Af - (float)(2.0 * (dot0 + dot1))) + Btab[k];
            if (s < bsv) { bsv = s; bsk = k; }
        }
        #pragma unroll
        for (int mm = 1; mm < 64; mm <<= 1) {
            float ov = __shfl_xor(bsv, mm);
            int oi = __shfl_xor(bsk, mm);
            if (ov < bsv || (ov == bsv && oi < bsk)) { bsv = ov; bsk = oi; }
        }
        if (lane == 0) { rv[wave] = bsv; ri[wave] = bsk; }
        __syncthreads();
        if (tid == 0) {
            float bv = rv[0]; int bk = ri[0];
            #pragma unroll
            for (int wv = 1; wv < 4; ++wv) {
                if (rv[wv] < bv || (rv[wv] == bv && ri[wv] < bk)) { bv = rv[wv]; bk = ri[wv]; }
            }
            out[IDX_OFF + gidx] = (float)bk;
        }
        __syncthreads();
    }

    // ---- phase 2: cand rescores (wave per entry, grid-strided) ----
    const unsigned nc = *reinterpret_cast<const unsigned*>(out + CNT_OFF);
    const uint4* clist = reinterpret_cast<const uint4*>(out + CAND_OFF);
    for (unsigned ei = blockIdx.x * 4 + wave; ei < nc; ei += gridDim.x * 4) {
        uint4 ent = clist[ei];
        const int gidx = (int)ent.x;
        const int c1 = (int)(ent.y & 0xFFFFu), c2 = (int)(ent.y >> 16);
        const int c3 = (int)(ent.z & 0xFFFFu), c4 = (int)(ent.z >> 16);
        const int b = gidx >> 14, m = gidx & (MB - 1);
        const float* zr = z + (size_t)b * DIM * MB + m;
        const float* e1 = e + (size_t)c1 * DIM;
        const float* e2 = e + (size_t)c2 * DIM;
        const float* e3 = e + (size_t)c3 * DIM;
        const float* e4 = e + (size_t)c4 * DIM;
        double A = 0.0;
        double d1 = 0.0, d2 = 0.0, d3 = 0.0, d4 = 0.0;
        #pragma unroll
        for (int jj = 0; jj < 4; ++jj) {
            int d = lane * 4 + jj;
            double zv = (double)zr[(size_t)d * MB];
            A = fma(zv, zv, A);
            d1 = fma(zv, (double)e1[d], d1);
            d2 = fma(zv, (double)e2[d], d2);
            d3 = fma(zv, (double)e3[d], d3);
            d4 = fma(zv, (double)e4[d], d4);
        }
        #pragma unroll
        for (int mm = 1; mm < 64; mm <<= 1) {
            A += __shfl_xor(A, mm);
            d1 += __shfl_xor(d1, mm); d2 += __shfl_xor(d2, mm);
            d3 += __shfl_xor(d3, mm); d4 += __shfl_xor(d4, mm);
        }
        if (lane == 0) {
            float Af = (float)A;
            float s1 = (Af - (float)(2.0 * d1)) + Btab[c1];
            float s2 = (Af - (float)(2.0 * d2)) + Btab[c2];
            float s3 = (Af - (float)(2.0 * d3)) + Btab[c3];
            float s4 = (Af - (float)(2.0 * d4)) + Btab[c4];
            float bv = s1; int bk = c1;
            if (lexlt(s2, c2, bv, bk)) { bv = s2; bk = c2; }
            if (lexlt(s3, c3, bv, bk)) { bv = s3; bk = c3; }
            if (lexlt(s4, c4, bv, bk)) { bv = s4; bk = c4; }
            out[IDX_OFF + gidx] = (float)bk;
        }
    }
}

// ---- K3: z_q scatter + fused loss; e-rows staged in LDS (R21-proven) ----
__global__ __launch_bounds__(256) void vq_apply(const float* __restrict__ z,
                                                const float* __restrict__ e,
                                                float* __restrict__ out) {
    __shared__ int lds_fi[64];
    __shared__ float lds_e[64][260];
    __shared__ double lds_ls[4];
    const int tid = threadIdx.x;
    const int wave = tid >> 6, lane = tid & 63;
    const int nbase = blockIdx.x * 64;
    const int b = nbase / MB;
    const int mbase = nbase % MB;
    if (tid < 64) lds_fi[tid] = (int)out[IDX_OFF + nbase + tid];
    __syncthreads();
    for (int r = wave; r < 64; r += 4) {
        int code = lds_fi[r];
        float4 v = reinterpret_cast<const float4*>(e + (size_t)code * DIM)[lane];
        *reinterpret_cast<float4*>(&lds_e[r][lane * 4]) = v;
    }
    __syncthreads();

    double lsum = 0.0;
    const int mloc = tid & 63;
    const int d0 = tid >> 6;
    #pragma unroll 4
    for (int d = d0; d < DIM; d += 4) {
        float ev = lds_e[mloc][d];
        size_t off = (size_t)b * (DIM * MB) + (size_t)d * MB + mbase + mloc;
        float zv = z[off];
        out[off] = ev;
        float diff = ev - zv;
        lsum += (double)diff * diff;
    }
    #pragma unroll
    for (int off = 32; off > 0; off >>= 1) lsum += __shfl_down(lsum, off);
    if (lane == 0) lds_ls[wave] = lsum;
    __syncthreads();
    if (tid == 0) {
        double t = lds_ls[0] + lds_ls[1] + lds_ls[2] + lds_ls[3];
        atomicAdd(out + LOSS_OFF, (float)(t * (1.25 / (double)ZELEMS)));
    }
}

extern "C" void kernel_launch(void* const* d_in, const int* in_sizes, int n_in,
                              void* d_out, int out_size, void* d_ws, size_t ws_size,
                              hipStream_t stream) {
    const float* z = (const float*)d_in[0];    // [4,256,16,32,32] fp32
    const float* e = (const float*)d_in[1];    // [4096,256] fp32
    float* out = (float*)d_out;

    hipMemsetAsync(out + LOSS_OFF, 0, sizeof(float), stream);
    hipMemsetAsync(out + CNT_OFF, 0, 2 * sizeof(unsigned), stream);
    vq_prep<<<1536, 256, 0, stream>>>(e, out);
    vq_fast<<<(NTOT / 64) * 2, 256, 0, stream>>>(z, out);
    vq_merge<<<NTOT / 256, 256, 0, stream>>>(out);
    vq_resolve<<<1024, 256, 0, stream>>>(z, e, out);
    vq_apply<<<NTOT / 64, 256, 0, stream>>>(z, e, out);
}

// Round 27
// 425.837 us; speedup vs baseline: 1.0613x; 1.0613x over previous
//
#include <hip/hip_runtime.h>
#include <float.h>

#define KC 4096
#define DIM 256
#define MB 16384            // m per batch element (16*32*32)
#define NTOT 65536          // rows
#define ZELEMS 16777216
#define LOSS_OFF 16777216
#define IDX_OFF  16777217
// TAU: 2*(grid ULP(256)=3.05e-5) + 2*fp16-chain score err (<=4.7e-5 worst) + slack.
// Validated empirically at 1.5e-4 in R11-R26 (0 misses across 65536 rows).
#define TAU 1.5e-4f

// scratch inside z_q output region (fully overwritten by vq_apply at the end):
// [0, 524288)       fp16 e' A-fragment table (2MB)
#define BT_OFF   524288     // f32 |e_k|^2 table, 4096 floats
#define CNT_OFF  528400     // 2 uints (cand count, full count)
#define CAND_OFF 532480     // uint4 entries (16B each), cap 65536
#define FULL_OFF 800000     // uint entries, cap 65536

typedef _Float16 h8 __attribute__((ext_vector_type(8)));
typedef float f4v __attribute__((ext_vector_type(4)));

__device__ __forceinline__ bool lexlt(float av, int ai, float bv, int bi) {
    return (av < bv) || (av == bv && ai < bi);
}

// ---- P: fused prep. Blocks 0-511: fp16 e'=e*4096 A-frag table (R10-R25
// verified geometry). Blocks 512-1535: |e|^2 (fp64->f32), one wave per code. ----
__global__ __launch_bounds__(256) void vq_prep(const float* __restrict__ e,
                                               float* __restrict__ out) {
    if (blockIdx.x < 512) {
        int t = blockIdx.x * 256 + threadIdx.x;        // 0..131071
        int code = t >> 5, s8 = t & 31;
        const float4* src = reinterpret_cast<const float4*>(e + (size_t)code * DIM + s8 * 8);
        float4 v0 = src[0], v1 = src[1];
        float f[8] = {v0.x, v0.y, v0.z, v0.w, v1.x, v1.y, v1.z, v1.w};
        union { uint4 q; _Float16 h[8]; } P;
        #pragma unroll
        for (int p = 0; p < 8; ++p) P.h[p] = (_Float16)(f[p] * 4096.0f);
        int kc = s8 >> 2, khi = s8 & 3;
        int lane = khi * 16 + (code & 15);
        int slot = ((code >> 4) * 8 + kc) * 64 + lane;
        reinterpret_cast<uint4*>(out)[slot] = P.q;
    } else {
        int k = (blockIdx.x - 512) * 4 + (threadIdx.x >> 6);   // 0..4095
        int lane = threadIdx.x & 63;
        float4 v = reinterpret_cast<const float4*>(e + (size_t)k * DIM)[lane];
        double s = (double)v.x * v.x + (double)v.y * v.y + (double)v.z * v.z + (double)v.w * v.w;
        #pragma unroll
        for (int off = 32; off > 0; off >>= 1) s += __shfl_down(s, off);
        if (lane == 0) out[BT_OFF + k] = (float)s;
    }
}

// sorted insert keeping the 4 SMALLEST pushed (v0<=v1<=v2<=v3); exact-loss
// guarantee (R18-validated): any evicted value >= v3, so a lost window member
// forces v3<=thr -> n=5 -> full. No overflow counter needed.
#define INS4(V0, V1, V2, V3, L0, L1, L2, L3, v, k)                              \
    if (v < V3) {                                                               \
        if (v < V2) {                                                           \
            V3 = V2; L3 = L2;                                                   \
            if (v < V1) {                                                       \
                V2 = V1; L2 = L1;                                               \
                if (v < V0) { V1 = V0; L1 = L0; V0 = v; L0 = k; }               \
                else        { V1 = v; L1 = k; }                                 \
            } else { V2 = v; L2 = k; }                                          \
        } else { V3 = v; L3 = k; }                                              \
    }

// ---- K1: fp16 MFMA, single-pass exact-window (R18 classifier).
// Block = 64 rows (4 waves x 16 rows, ONE row-set per wave) -> 1024 blocks
// = 4 blocks/CU, 16-code tiles, 18.4KB LDS, 48 VGPR (R21-proven best). ----
__global__ __launch_bounds__(256) void vq_fast(const float* __restrict__ z,
                                               float* __restrict__ out) {
    __shared__ uint4 etile[2][512];                // 16KB double-buffered tile
    __shared__ unsigned long long lists[4][16][4]; // (wave,row,khi) packed lists
    const int tid = threadIdx.x;
    const int wave = tid >> 6, lane = tid & 63;
    const int khi = lane >> 4, l16 = lane & 15;
    const int nbase = blockIdx.x * 64;
    const int b = nbase / MB;
    const int mbase = nbase % MB;
    const float* zb = z + (size_t)b * DIM * MB + mbase + wave * 16 + l16;

    // z B-fragments (fp16), 1 row-set x 8 kc
    h8 zf[8];
    #pragma unroll
    for (int kc = 0; kc < 8; ++kc) {
        h8 va;
        #pragma unroll
        for (int j = 0; j < 8; ++j)
            va[j] = (_Float16)zb[(size_t)(kc * 32 + khi * 8 + j) * MB];
        zf[kc] = va;
    }

    const uint4* ET = reinterpret_cast<const uint4*>(out);
    const float* Btab = out + BT_OFF;

    float b1 = FLT_MAX;
    int bk = 0;
    float v0 = FLT_MAX, v1 = FLT_MAX, v2 = FLT_MAX, v3 = FLT_MAX;
    int l0 = 0, l1 = 0, l2 = 0, l3 = 0;

    uint4 r0 = ET[tid], r1 = ET[tid + 256];        // preload tile 0
    for (int tile = 0; tile < KC / 16; ++tile) {
        const int cur = tile & 1;
        etile[cur][tid] = r0; etile[cur][tid + 256] = r1;
        __syncthreads();                           // only barrier per tile
        if (tile < KC / 16 - 1) {
            r0 = ET[(size_t)(tile + 1) * 512 + tid];
            r1 = ET[(size_t)(tile + 1) * 512 + tid + 256];
        }

        // 2 independent MFMA chains (kc even/odd)
        f4v ae = {0.f, 0.f, 0.f, 0.f}, ao = ae;
        #pragma unroll
        for (int kc = 0; kc < 8; kc += 2) {
            union { uint4 q; h8 v; } afe, afo;
            afe.q = etile[cur][kc * 64 + lane];
            afo.q = etile[cur][(kc + 1) * 64 + lane];
            ae = __builtin_amdgcn_mfma_f32_16x16x32_f16(afe.v, zf[kc], ae, 0, 0, 0);
            ao = __builtin_amdgcn_mfma_f32_16x16x32_f16(afo.v, zf[kc + 1], ao, 0, 0, 0);
        }

        const f4v Bv = *reinterpret_cast<const f4v*>(Btab + tile * 16 + khi * 4);
        const int kb = tile * 16 + khi * 4;
        float sc[4];
        #pragma unroll
        for (int i = 0; i < 4; ++i)
            sc[i] = fmaf(-4.8828125e-4f, ae[i] + ao[i], Bv[i]);    // -1/2048 exact
        float m = fminf(fminf(sc[0], sc[1]), fminf(sc[2], sc[3]));
        if (m <= b1 + TAU) {                       // rare: detail insert
            #pragma unroll
            for (int i = 0; i < 4; ++i) {
                float s = sc[i]; int k = kb + i;   // ascending k per lane
                if (s < b1) {
                    if (b1 <= s + TAU) INS4(v0, v1, v2, v3, l0, l1, l2, l3, b1, bk)
                    b1 = s; bk = k;
                } else if (s <= b1 + TAU) {
                    INS4(v0, v1, v2, v3, l0, l1, l2, l3, s, k)
                }
            }
        }
    }

    // merge top-1 across the 4 khi groups (lex), keep own (b1,bk) intact
    float gb = b1;
    int gk = bk;
    #pragma unroll
    for (int off = 16; off < 64; off <<= 1) {
        float ov = __shfl_xor(gb, off); int ok = __shfl_xor(gk, off);
        if (lexlt(ov, ok, gb, gk)) { gb = ov; gk = ok; }
    }
    const float thr = gb + TAU;

    // exact-filter own entries vs FINAL threshold, pack (<=4 ks + count<=5)
    int n = 0, pa = 0, pb = 0, pc = 0, pd = 0;
    #define ADDW(kk) { if (n == 0) pa = kk; else if (n == 1) pb = kk; \
                       else if (n == 2) pc = kk; else if (n == 3) pd = kk; n++; }
    if (b1 <= thr) ADDW(bk)
    if (v0 <= thr) ADDW(l0)
    if (v1 <= thr) ADDW(l1)
    if (v2 <= thr) ADDW(l2)
    if (v3 <= thr) ADDW(l3)
    lists[wave][l16][khi] = ((unsigned long long)n << 48) |
        (unsigned long long)pa | ((unsigned long long)pb << 12) |
        ((unsigned long long)pc << 24) | ((unsigned long long)pd << 36);
    __syncthreads();

    // gather + classify + emit (lanes<16 own one row)
    unsigned* cntg = (unsigned*)(out + CNT_OFF);
    {
        bool act = (lane < 16);
        int gidx = nbase + wave * 16 + l16;
        int I1 = gk;
        int tot = 0, c[4];
        c[0] = c[1] = c[2] = c[3] = I1;            // pad with best (harmless dup)
        if (act) {
            #pragma unroll
            for (int q = 0; q < 4; ++q) {
                unsigned long long pl = lists[wave][l16][q];
                int pcnt = (int)(pl >> 48);
                #pragma unroll
                for (int j = 0; j < 4; ++j) {
                    int kv = (int)((pl >> (12 * j)) & 4095ull);
                    if (j < pcnt && tot + j < 4) c[tot + j] = kv;
                }
                tot += pcnt;
            }
            out[IDX_OFF + gidx] = (float)I1;       // final for clean; placeholder else
        }
        bool cand = act && (tot >= 2) && (tot <= 4);
        bool full = act && (tot > 4);
        unsigned long long mc = __ballot(cand);
        if (mc) {
            int leader = __ffsll((long long)mc) - 1;
            unsigned base = 0;
            if (lane == leader) base = atomicAdd(cntg, (unsigned)__popcll(mc));
            base = __shfl(base, leader);
            if (cand) {
                unsigned pos = base + (unsigned)__popcll(mc & ((1ull << lane) - 1ull));
                reinterpret_cast<uint4*>(out + CAND_OFF)[pos] =
                    make_uint4((unsigned)gidx,
                               (unsigned)c[0] | ((unsigned)c[1] << 16),
                               (unsigned)c[2] | ((unsigned)c[3] << 16), 0u);
            }
        }
        unsigned long long mf = __ballot(full);
        if (mf) {
            int leader = __ffsll((long long)mf) - 1;
            unsigned base = 0;
            if (lane == leader) base = atomicAdd(cntg + 1, (unsigned)__popcll(mf));
            base = __shfl(base, leader);
            if (full) {
                unsigned pos = base + (unsigned)__popcll(mf & ((1ull << lane) - 1ull));
                reinterpret_cast<unsigned*>(out + FULL_OFF)[pos] = (unsigned)gidx;
            }
        }
    }
}

// ---- K2: fused resolver. All blocks: full entries (block-strided), then
// cand entries (wave-strided). Both use the R5-exact formula, B from Btab. ----
__global__ __launch_bounds__(256) void vq_resolve(const float* __restrict__ z,
                                                  const float* __restrict__ e,
                                                  float* __restrict__ out) {
    __shared__ float zs[DIM];
    __shared__ float rv[4];
    __shared__ int ri[4];
    const int tid = threadIdx.x;
    const int wave = tid >> 6, lane = tid & 63;
    const float* Btab = out + BT_OFF;

    // ---- phase 1: full rescans (block per entry, grid-strided) ----
    const unsigned nf = reinterpret_cast<const unsigned*>(out + CNT_OFF)[1];
    const unsigned* flist = reinterpret_cast<const unsigned*>(out + FULL_OFF);
    for (unsigned ei = blockIdx.x; ei < nf; ei += gridDim.x) {
        const int gidx = (int)flist[ei];
        const int b = gidx >> 14, m = gidx & (MB - 1);
        const float* zr = z + (size_t)b * DIM * MB + m;
        if (tid < DIM) zs[tid] = zr[(size_t)tid * MB];
        __syncthreads();
        double av = 0.0;
        #pragma unroll
        for (int t2 = 0; t2 < 4; ++t2) {
            double zv = (double)zs[lane * 4 + t2];
            av = fma(zv, zv, av);
        }
        #pragma unroll
        for (int mm = 1; mm < 64; mm <<= 1) av += __shfl_xor(av, mm);
        const float Af = (float)av;

        float bsv = FLT_MAX; int bsk = 0;
        for (int kk = 0; kk < 16; ++kk) {
            const int k = kk * 256 + tid;          // ascending per thread
            const float4* er4 = reinterpret_cast<const float4*>(e + (size_t)k * DIM);
            const float4* zs4 = reinterpret_cast<const float4*>(zs);
            double dot0 = 0.0, dot1 = 0.0;
            #pragma unroll 8
            for (int d4 = 0; d4 < 64; ++d4) {
                float4 ev = er4[d4];
                float4 zv = zs4[d4];
                dot0 = fma((double)zv.x, (double)ev.x, dot0);
                dot1 = fma((double)zv.y, (double)ev.y, dot1);
                dot0 = fma((double)zv.z, (double)ev.z, dot0);
                dot1 = fma((double)zv.w, (double)ev.w, dot1);
            }
            float s = (Af - (float)(2.0 * (dot0 + dot1))) + Btab[k];
            if (s < bsv) { bsv = s; bsk = k; }
        }
        #pragma unroll
        for (int mm = 1; mm < 64; mm <<= 1) {
            float ov = __shfl_xor(bsv, mm);
            int oi = __shfl_xor(bsk, mm);
            if (ov < bsv || (ov == bsv && oi < bsk)) { bsv = ov; bsk = oi; }
        }
        if (lane == 0) { rv[wave] = bsv; ri[wave] = bsk; }
        __syncthreads();
        if (tid == 0) {
            float bv = rv[0]; int bk = ri[0];
            #pragma unroll
            for (int wv = 1; wv < 4; ++wv) {
                if (rv[wv] < bv || (rv[wv] == bv && ri[wv] < bk)) { bv = rv[wv]; bk = ri[wv]; }
            }
            out[IDX_OFF + gidx] = (float)bk;
        }
        __syncthreads();
    }

    // ---- phase 2: cand rescores (wave per entry, grid-strided) ----
    const unsigned nc = *reinterpret_cast<const unsigned*>(out + CNT_OFF);
    const uint4* clist = reinterpret_cast<const uint4*>(out + CAND_OFF);
    for (unsigned ei = blockIdx.x * 4 + wave; ei < nc; ei += gridDim.x * 4) {
        uint4 ent = clist[ei];
        const int gidx = (int)ent.x;
        const int c1 = (int)(ent.y & 0xFFFFu), c2 = (int)(ent.y >> 16);
        const int c3 = (int)(ent.z & 0xFFFFu), c4 = (int)(ent.z >> 16);
        const int b = gidx >> 14, m = gidx & (MB - 1);
        const float* zr = z + (size_t)b * DIM * MB + m;
        const float* e1 = e + (size_t)c1 * DIM;
        const float* e2 = e + (size_t)c2 * DIM;
        const float* e3 = e + (size_t)c3 * DIM;
        const float* e4 = e + (size_t)c4 * DIM;
        double A = 0.0;
        double d1 = 0.0, d2 = 0.0, d3 = 0.0, d4 = 0.0;
        #pragma unroll
        for (int jj = 0; jj < 4; ++jj) {
            int d = lane * 4 + jj;
            double zv = (double)zr[(size_t)d * MB];
            A = fma(zv, zv, A);
            d1 = fma(zv, (double)e1[d], d1);
            d2 = fma(zv, (double)e2[d], d2);
            d3 = fma(zv, (double)e3[d], d3);
            d4 = fma(zv, (double)e4[d], d4);
        }
        #pragma unroll
        for (int mm = 1; mm < 64; mm <<= 1) {
            A += __shfl_xor(A, mm);
            d1 += __shfl_xor(d1, mm); d2 += __shfl_xor(d2, mm);
            d3 += __shfl_xor(d3, mm); d4 += __shfl_xor(d4, mm);
        }
        if (lane == 0) {
            float Af = (float)A;
            float s1 = (Af - (float)(2.0 * d1)) + Btab[c1];
            float s2 = (Af - (float)(2.0 * d2)) + Btab[c2];
            float s3 = (Af - (float)(2.0 * d3)) + Btab[c3];
            float s4 = (Af - (float)(2.0 * d4)) + Btab[c4];
            float bv = s1; int bk = c1;
            if (lexlt(s2, c2, bv, bk)) { bv = s2; bk = c2; }
            if (lexlt(s3, c3, bv, bk)) { bv = s3; bk = c3; }
            if (lexlt(s4, c4, bv, bk)) { bv = s4; bk = c4; }
            out[IDX_OFF + gidx] = (float)bk;
        }
    }
}

// ---- K3: z_q scatter + fused loss; e-rows staged in LDS (R21-proven) ----
__global__ __launch_bounds__(256) void vq_apply(const float* __restrict__ z,
                                                const float* __restrict__ e,
                                                float* __restrict__ out) {
    __shared__ int lds_fi[64];
    __shared__ float lds_e[64][260];
    __shared__ double lds_ls[4];
    const int tid = threadIdx.x;
    const int wave = tid >> 6, lane = tid & 63;
    const int nbase = blockIdx.x * 64;
    const int b = nbase / MB;
    const int mbase = nbase % MB;
    if (tid < 64) lds_fi[tid] = (int)out[IDX_OFF + nbase + tid];
    __syncthreads();
    for (int r = wave; r < 64; r += 4) {
        int code = lds_fi[r];
        float4 v = reinterpret_cast<const float4*>(e + (size_t)code * DIM)[lane];
        *reinterpret_cast<float4*>(&lds_e[r][lane * 4]) = v;
    }
    __syncthreads();

    double lsum = 0.0;
    const int mloc = tid & 63;
    const int d0 = tid >> 6;
    #pragma unroll 4
    for (int d = d0; d < DIM; d += 4) {
        float ev = lds_e[mloc][d];
        size_t off = (size_t)b * (DIM * MB) + (size_t)d * MB + mbase + mloc;
        float zv = z[off];
        out[off] = ev;
        float diff = ev - zv;
        lsum += (double)diff * diff;
    }
    #pragma unroll
    for (int off = 32; off > 0; off >>= 1) lsum += __shfl_down(lsum, off);
    if (lane == 0) lds_ls[wave] = lsum;
    __syncthreads();
    if (tid == 0) {
        double t = lds_ls[0] + lds_ls[1] + lds_ls[2] + lds_ls[3];
        atomicAdd(out + LOSS_OFF, (float)(t * (1.25 / (double)ZELEMS)));
    }
}

extern "C" void kernel_launch(void* const* d_in, const int* in_sizes, int n_in,
                              void* d_out, int out_size, void* d_ws, size_t ws_size,
                              hipStream_t stream) {
    const float* z = (const float*)d_in[0];    // [4,256,16,32,32] fp32
    const float* e = (const float*)d_in[1];    // [4096,256] fp32
    float* out = (float*)d_out;

    hipMemsetAsync(out + LOSS_OFF, 0, sizeof(float), stream);
    hipMemsetAsync(out + CNT_OFF, 0, 2 * sizeof(unsigned), stream);
    vq_prep<<<1536, 256, 0, stream>>>(e, out);
    vq_fast<<<NTOT / 64, 256, 0, stream>>>(z, out);
    vq_resolve<<<1024, 256, 0, stream>>>(z, e, out);
    vq_apply<<<NTOT / 64, 256, 0, stream>>>(z, e, out);
}